// Round 11
// baseline (621.267 us; speedup 1.0000x reference)
//
#include <hip/hip_runtime.h>
#include <hip/hip_cooperative_groups.h>
#include <stdint.h>

namespace cg = cooperative_groups;

#define BATCH 16
#define H 512
#define W 512
#define HW (H * W)
#define NTOT (BATCH * HW)
#define NWORDS (NTOT / 64)      // 65536 packed words, 8 per row, 4096 per image

#define TPB 256
#define NBLK ((NTOT + TPB - 1) / TPB)

#define SROWS 16                // CCL strip = 16 rows
#define SWORDS 128              // words per CCL strip (= threads per mega block)
#define SPIX 8192               // pixels per CCL strip
#define NSTRIPS (NWORDS / SWORDS)   // 512 strips (never straddle images)

// ---------------------------------------------------------------------------
// Union-find (global): atomicMin keeps parent <= child (monotone) -> acyclic;
// stale plain reads only cost retries. find_root_c path-compresses.
// ---------------------------------------------------------------------------
__device__ __forceinline__ int find_root_c(int* L, int x) {
    int r = x, p = L[r];
    while (p != r) { r = p; p = L[r]; }
    if (L[x] != r) atomicMin(&L[x], r);
    return r;
}

__device__ void merge_uf(int* L, int a, int b) {
    while (true) {
        a = find_root_c(L, a);
        b = find_root_c(L, b);
        if (a == b) return;
        int lo = a < b ? a : b;
        int hi = a < b ? b : a;
        int old = atomicMin(&L[hi], lo);
        if (old == hi) return;
        a = lo; b = old;
    }
}

__device__ __forceinline__ int find_root_lds(int* P, int x) {
    int r = x, p = P[r];
    while (p != r) { r = p; p = P[r]; }
    return r;
}

__device__ void merge_lds(int* P, int a, int b) {
    while (true) {
        a = find_root_lds(P, a);
        b = find_root_lds(P, b);
        if (a == b) return;
        int lo = a < b ? a : b;
        int hi = a < b ? b : a;
        int old = atomicMin(&P[hi], lo);
        if (old == hi) return;
        a = lo; b = old;
    }
}

// start index of the run containing bit i of word m (base = pixel idx of bit0)
__device__ __forceinline__ int start_of(uint64_t m, int i, int cv, int base) {
    uint64_t below = i ? ((~m) & ((1ull << i) - 1)) : 0ull;
    if (below == 0) return (cv >= 0) ? cv : base;
    int hz = 63 - __builtin_clzll(below);
    return base + hz + 1;
}

// remove-small transform of one word (fg comps; pure function of CCL data)
__device__ uint64_t keep_word(const uint64_t* __restrict__ bits,
                              const int* __restrict__ carry, const int* __restrict__ L,
                              const int* __restrict__ sizes, const int* __restrict__ ncomp,
                              int minsz, int gw) {
    uint64_t m = bits[gw];
    uint64_t res = m;
    if (m && ncomp[gw >> 12] > 1) {
        int cv = carry[gw];
        int base = gw << 6;
        while (m) {
            int s = __builtin_ctzll(m);
            uint64_t rest = m >> s;
            uint64_t nr = ~rest;
            int len = nr ? __builtin_ctzll(nr) : (64 - s);
            uint64_t piece = ((len >= 64) ? ~0ull : ((1ull << len) - 1)) << s;
            int start = (s == 0 && cv >= 0) ? cv : (base + s);
            if (sizes[L[start]] < minsz) res &= ~piece;
            m &= ~piece;
        }
    }
    return res;
}

// fill-holes transform of one word (bg comps; needs inv=1 CCL data)
__device__ uint64_t fill_word(const uint64_t* __restrict__ bits,
                              const int* __restrict__ carry, const int* __restrict__ L,
                              const int* __restrict__ sizes, int minsz, int gw) {
    uint64_t fg = bits[gw];
    uint64_t bg = ~fg;
    uint64_t res = fg;
    int cv = carry[gw];
    int base = gw << 6;
    while (bg) {
        int s = __builtin_ctzll(bg);
        uint64_t rest = bg >> s;
        uint64_t nr = ~rest;
        int len = nr ? __builtin_ctzll(nr) : (64 - s);
        uint64_t piece = ((len >= 64) ? ~0ull : ((1ull << len) - 1)) << s;
        int start = (s == 0 && cv >= 0) ? cv : (base + s);
        if (sizes[L[start]] < minsz) res |= piece;
        bg &= ~piece;
    }
    return res;
}

// one morph output word from an LDS window; gyTop = global row of local row 0
template <int R, bool ERODE>
__device__ uint64_t morph_word_lds(const uint64_t* buf, int lrow, int w, int gyTop) {
    const uint64_t BORDER = ERODE ? ~0ull : 0ull;
    uint64_t res = ERODE ? ~0ull : 0ull;
#pragma unroll
    for (int dy = -R; dy <= R; ++dy) {
        int lr = lrow + dy;
        int gy = gyTop + lr;
        if (gy < 0 || gy >= H) continue;       // image border rows = identity
        int v = R * R - dy * dy;
        int kx = 0;
        while ((kx + 1) * (kx + 1) <= v) ++kx;
        uint64_t cur = buf[lr * 8 + w];
        uint64_t prv = (w > 0) ? buf[lr * 8 + w - 1] : BORDER;
        uint64_t nxt = (w < 7) ? buf[lr * 8 + w + 1] : BORDER;
        uint64_t acc = cur;
#pragma unroll
        for (int dx = 1; dx <= kx; ++dx) {
            uint64_t right = (cur >> dx) | (nxt << (64 - dx));
            uint64_t left  = (cur << dx) | (prv >> (64 - dx));
            if (ERODE) acc &= right & left;
            else       acc |= right | left;
        }
        if (ERODE) res &= acc;
        else       res |= acc;
    }
    return res;
}

// ---------------------------------------------------------------------------
// Strip-local CCL body (128 threads, 16-row strip): all intra-strip unions in
// LDS, publish depth-1 trees. NOTE: par may alias other LDS buffers — its
// first write happens after the first internal __syncthreads, by which time
// every thread has finished reading any aliased data (reads precede the call).
// ---------------------------------------------------------------------------
__device__ void strip_ccl_body(uint64_t m, uint64_t* sw, int* scarry, int* par,
                               int blk, int t,
                               int* __restrict__ carry, int* __restrict__ L,
                               int* __restrict__ sizes, int* __restrict__ ncomp) {
    sw[t] = m;
    __syncthreads();

    if (t < SROWS) {                    // per-row carries
        int cv = -1;
        for (int i = 0; i < 8; ++i) {
            int lw = t * 8 + i;
            scarry[lw] = cv;
            uint64_t w = sw[lw];
            if (w >> 63) {
                uint64_t z = ~w;
                if (z == 0) { if (cv < 0) cv = lw << 6; }
                else { int hz = 63 - __builtin_clzll(z); cv = (lw << 6) + hz + 1; }
            } else cv = -1;
        }
    }
    __syncthreads();

    int cv = scarry[t];
    carry[blk * SWORDS + t] = (cv >= 0) ? (blk * SPIX + cv) : -1;
    int lbase = t << 6;
    uint64_t starts = m & ~((m << 1) | ((cv >= 0) ? 1ull : 0ull));
    uint64_t ss = starts;
    while (ss) {
        int s = __builtin_ctzll(ss);
        par[lbase + s] = lbase + s;
        ss &= ss - 1;
    }
    __syncthreads();

    if (t >= 8 && m) {                  // intra-strip vertical unions
        uint64_t up = sw[t - 8];
        uint64_t cand = m & up;
        if (cand) {
            uint64_t curprev = (t & 7) ? sw[t - 1] : 0ull;
            uint64_t upprev  = (t & 7) ? sw[t - 9] : 0ull;
            uint64_t curl = (m << 1) | (curprev >> 63);
            uint64_t upl  = (up << 1) | (upprev >> 63);
            cand &= ~(curl & upl);
            int cvu = scarry[t - 8];
            while (cand) {
                int i = __builtin_ctzll(cand);
                int sP = start_of(m, i, cv, lbase);
                int sQ = start_of(up, i, cvu, lbase - 512);
                merge_lds(par, sP, sQ);
                cand &= cand - 1;
            }
        }
    }
    __syncthreads();

    int gpix = blk * SPIX;              // publish depth-1 trees
    ss = starts;
    while (ss) {
        int s = __builtin_ctzll(ss);
        int ls = lbase + s;
        int r = find_root_lds(par, ls);
        L[gpix + ls] = gpix + r;
        if (r == ls) sizes[gpix + ls] = 0;
        ss &= ss - 1;
    }
    if (t == 0 && (blk & 31) == 0) ncomp[blk >> 5] = 0;   // 32 strips per image
}

// Cross-strip boundary unions (flat-id mapping; 16 imgs x 31 rows x 8 words)
__device__ void merge_bound_dev(const uint64_t* __restrict__ bits, int inv,
                                const int* __restrict__ carry, int* __restrict__ L,
                                int flat) {
    if (flat >= BATCH * 31 * 8) return;
    int img = flat / 248;
    int rem = flat - img * 248;
    int y = ((rem >> 3) + 1) * SROWS;
    int w = rem & 7;
    int gw = img * 4096 + y * 8 + w;
    uint64_t inv64 = inv ? ~0ull : 0ull;
    uint64_t cur = bits[gw] ^ inv64;
    uint64_t up  = bits[gw - 8] ^ inv64;
    uint64_t cand = cur & up;
    if (!cand) return;
    uint64_t curprev = w ? (bits[gw - 1] ^ inv64) : 0ull;
    uint64_t upprev  = w ? (bits[gw - 9] ^ inv64) : 0ull;
    uint64_t curl = (cur << 1) | (curprev >> 63);
    uint64_t upl  = (up << 1)  | (upprev >> 63);
    cand &= ~(curl & upl);
    if (!cand) return;
    int cvc = carry[gw], cvu = carry[gw - 8];
    int base = gw << 6;
    while (cand) {
        int i = __builtin_ctzll(cand);
        int sP = start_of(cur, i, cvc, base);
        int sQ = start_of(up, i, cvu, base - W);
        merge_uf(L, sP, sQ);
        cand &= cand - 1;
    }
}

// Word-granular flatten + size accumulation with per-block LDS hash (128 thr).
__device__ void flatten_count_dev(const uint64_t* __restrict__ bits, int inv,
                                  const int* __restrict__ carry, int* __restrict__ L,
                                  int* __restrict__ sizes, int* __restrict__ ncomp,
                                  int gw, int t, int* hk, int* hv) {
    hk[t] = -1; hv[t] = 0;
    __syncthreads();
    uint64_t inv64 = inv ? ~0ull : 0ull;
    uint64_t m = bits[gw] ^ inv64;
    if (m) {
        int cv = carry[gw];
        int base = gw << 6;
        while (m) {
            int s = __builtin_ctzll(m);
            uint64_t rest = m >> s;
            uint64_t nr = ~rest;
            int len = nr ? __builtin_ctzll(nr) : (64 - s);
            uint64_t piece = ((len >= 64) ? ~0ull : ((1ull << len) - 1)) << s;
            bool initial = !(s == 0 && cv >= 0);
            int start = initial ? (base + s) : cv;
            int r = find_root_c(L, start);
            if (initial && r == start) atomicAdd(&ncomp[gw >> 12], 1);
            int cnt = __popcll(piece);
            uint32_t h = ((uint32_t)r * 2654435761u) >> 25;
            bool done = false;
            for (int tt = 0; tt < 16; ++tt) {
                int slot = (h + tt) & 127;
                int k = hk[slot];
                if (k == -1) k = atomicCAS(&hk[slot], -1, r);
                if (k == -1 || k == r) { atomicAdd(&hv[slot], cnt); done = true; break; }
            }
            if (!done) atomicAdd(&sizes[r], cnt);
            m &= ~piece;
        }
    }
    __syncthreads();
    if (hk[t] != -1) atomicAdd(&sizes[hk[t]], hv[t]);
    __syncthreads();
}

// ---------------------------------------------------------------------------
// Kernels
// ---------------------------------------------------------------------------
__global__ void k_thresh_pack(const float* __restrict__ in, uint64_t* __restrict__ bits) {
    int p = blockIdx.x * blockDim.x + threadIdx.x;
    bool a = (p < NTOT) && (in[p] > 0.0f);
    uint64_t b = __ballot(a);
    if ((threadIdx.x & 63) == 0 && p < NTOT) bits[p >> 6] = b;
}

// Cooperative mega-kernel: CCL1, keep1+CCL2, fill+morph chain, CCL3 — all the
// middle pipeline in one dispatch with grid.sync() between cross-block phases.
__global__ __launch_bounds__(SWORDS, 2)
void k_mega(const uint64_t* __restrict__ bits1, uint64_t* __restrict__ bits2,
            uint64_t* __restrict__ bits3,
            int* __restrict__ carryA, int* __restrict__ carryB,
            int* __restrict__ LA, int* __restrict__ LB,
            int* __restrict__ sizesA, int* __restrict__ sizesB,
            int* __restrict__ ncompA, int* __restrict__ ncompB) {
    cg::grid_group grid = cg::this_grid();
    __shared__ uint64_t sw[SWORDS];
    __shared__ int scarry[SWORDS];
    __shared__ int hk[128];
    __shared__ int hv[128];
    __shared__ union {
        int par[SPIX];                          // 32 KB, CCL phases
        struct { uint64_t A[320]; uint64_t B[320]; } mo;  // 5 KB, morph phase
    } U;
    int s = blockIdx.x;                 // strip id
    int t = threadIdx.x;                // word-in-strip
    int gw = s * SWORDS + t;
    int flat = s * SWORDS + t;          // flat id for boundary phases

    // P2: CCL1 strip (fg of bits1)
    strip_ccl_body(bits1[gw], sw, scarry, U.par, s, t, carryA, LA, sizesA, ncompA);
    grid.sync();
    // P3: CCL1 boundary unions
    merge_bound_dev(bits1, 0, carryA, LA, flat);
    grid.sync();
    // P4: CCL1 flatten + sizes + ncomp
    flatten_count_dev(bits1, 0, carryA, LA, sizesA, ncompA, gw, t, hk, hv);
    grid.sync();

    // P5: remove_small_objects(2000,guard) transform + CCL2 strip (bg)
    uint64_t kw = keep_word(bits1, carryA, LA, sizesA, ncompA, 2000, gw);
    bits2[gw] = kw;
    strip_ccl_body(~kw, sw, scarry, U.par, s, t, carryB, LB, sizesB, ncompB);
    grid.sync();
    // P6: CCL2 boundary unions
    merge_bound_dev(bits2, 1, carryB, LB, flat);
    grid.sync();
    // P7: CCL2 flatten
    flatten_count_dev(bits2, 1, carryB, LB, sizesB, ncompB, gw, t, hk, hv);
    grid.sync();

    // P8: fill_holes(<301) + erode(d2) + erode(d5) + dilate(d5), 40-row LDS
    uint64_t m3;
    {
        int img = s >> 5, si = s & 31;
        int gyTop = si * 16 - 12;
        for (int lw = t; lw < 320; lw += SWORDS) {
            int gy = gyTop + (lw >> 3);
            int w = lw & 7;
            uint64_t v = 0;
            if (gy >= 0 && gy < H)
                v = fill_word(bits2, carryB, LB, sizesB, 301, img * 4096 + gy * 8 + w);
            U.mo.A[lw] = v;
        }
        __syncthreads();
        for (int lw = t; lw < 320; lw += SWORDS) {
            int lr = lw >> 3;
            if (lr >= 2 && lr <= 37) U.mo.B[lw] = morph_word_lds<2, true>(U.mo.A, lr, lw & 7, gyTop);
        }
        __syncthreads();
        for (int lw = t; lw < 320; lw += SWORDS) {
            int lr = lw >> 3;
            if (lr >= 7 && lr <= 32) U.mo.A[lw] = morph_word_lds<5, true>(U.mo.B, lr, lw & 7, gyTop);
        }
        __syncthreads();
        for (int lw = t; lw < 320; lw += SWORDS) {
            int lr = lw >> 3;
            if (lr >= 12 && lr <= 27) U.mo.B[lw] = morph_word_lds<5, false>(U.mo.A, lr, lw & 7, gyTop);
        }
        __syncthreads();
        m3 = U.mo.B[t + 96];            // local rows 12..27 = this strip's rows
        bits3[gw] = m3;
    }
    // P9: CCL3 strip — feeds directly from LDS result, no grid.sync needed
    // (writes set A, last read in P5; all blocks are past P5 due to S4)
    strip_ccl_body(m3, sw, scarry, U.par, s, t, carryA, LA, sizesA, ncompA);
    grid.sync();
    // P10: CCL3 boundary unions
    merge_bound_dev(bits3, 0, carryA, LA, flat);
    grid.sync();
    // P11: CCL3 flatten
    flatten_count_dev(bits3, 0, carryA, LA, sizesA, ncompA, gw, t, hk, hv);
}

// FUSED: remove_small_objects transform + dilate(disk1) + float cast.
__global__ void k_keep_dilate_float(const uint64_t* __restrict__ bits,
                                    const int* __restrict__ carry, const int* __restrict__ L,
                                    const int* __restrict__ sizes, const int* __restrict__ ncomp,
                                    float* __restrict__ out) {
    __shared__ uint64_t kb[10 * 8];     // rows y0-1 .. y0+8
    __shared__ uint64_t db[8 * 8];      // dilated output rows
    int blk = blockIdx.x;
    int img = blk >> 6;                 // 64 blocks per image
    int s = blk & 63;
    int y0 = s * 8;
    int t = threadIdx.x;

    if (t < 80) {
        int lr = t >> 3;
        int w = t & 7;
        int gy = y0 - 1 + lr;
        uint64_t v = 0;
        if (gy >= 0 && gy < H)
            v = keep_word(bits, carry, L, sizes, ncomp, 2000, img * 4096 + gy * 8 + w);
        kb[t] = v;
    }
    __syncthreads();
    if (t < 64) {
        int r = t >> 3, w = t & 7;
        uint64_t cur = kb[(r + 1) * 8 + w];
        uint64_t up  = kb[r * 8 + w];
        uint64_t dn  = kb[(r + 2) * 8 + w];
        uint64_t prv = w ? kb[(r + 1) * 8 + w - 1] : 0ull;
        uint64_t nxt = (w < 7) ? kb[(r + 1) * 8 + w + 1] : 0ull;
        db[t] = cur | up | dn | (cur << 1) | (prv >> 63) | (cur >> 1) | (nxt << 63);
    }
    __syncthreads();

    int q0 = t * 16;                    // 16 consecutive pixels per thread
    uint64_t wd = db[q0 >> 6];
    int sh = q0 & 63;
    float4* o = (float4*)(out + (size_t)img * HW + (size_t)y0 * W + q0);
#pragma unroll
    for (int k = 0; k < 4; ++k) {
        uint32_t nib = (uint32_t)(wd >> (sh + k * 4)) & 0xFu;
        float4 f;
        f.x = (nib & 1u) ? 1.0f : 0.0f;
        f.y = (nib & 2u) ? 1.0f : 0.0f;
        f.z = (nib & 4u) ? 1.0f : 0.0f;
        f.w = (nib & 8u) ? 1.0f : 0.0f;
        o[k] = f;
    }
}

// ---------------------------------------------------------------------------
// Host side — 3 dispatches total
// ---------------------------------------------------------------------------
extern "C" void kernel_launch(void* const* d_in, const int* in_sizes, int n_in,
                              void* d_out, int out_size, void* d_ws, size_t ws_size,
                              hipStream_t stream) {
    const float* in = (const float*)d_in[0];
    float* out = (float*)d_out;

    uint8_t* ws = (uint8_t*)d_ws;
    int* LA      = (int*)ws;                                  // 16 MB
    int* sizesA  = (int*)(ws + (size_t)NTOT * 4);             // 16 MB
    int* LB      = (int*)(ws + (size_t)NTOT * 8);             // 16 MB
    int* sizesB  = (int*)(ws + (size_t)NTOT * 12);            // 16 MB
    uint64_t* bits1 = (uint64_t*)(ws + (size_t)NTOT * 16);    // 512 KB
    uint64_t* bits2 = bits1 + NWORDS;                         // 512 KB
    uint64_t* bits3 = bits2 + NWORDS;                         // 512 KB
    int* carryA = (int*)(bits3 + NWORDS);                     // 256 KB
    int* carryB = carryA + NWORDS;                            // 256 KB
    int* ncompA = carryB + NWORDS;                            // 64 B
    int* ncompB = ncompA + BATCH;                             // 64 B

    // 1) fg = mask > 0, packed (full-occupancy BW pass)
    k_thresh_pack<<<NBLK, TPB, 0, stream>>>(in, bits1);

    // 2) everything between the two 64MB passes, one cooperative dispatch
    void* args[] = { (void*)&bits1, (void*)&bits2, (void*)&bits3,
                     (void*)&carryA, (void*)&carryB, (void*)&LA, (void*)&LB,
                     (void*)&sizesA, (void*)&sizesB, (void*)&ncompA, (void*)&ncompB };
    hipLaunchCooperativeKernel((void*)k_mega, dim3(NSTRIPS), dim3(SWORDS),
                               args, 0, stream);

    // 3) remove_small_objects(2000,guard) + dilate(d1) + float4 out
    k_keep_dilate_float<<<BATCH * 64, TPB, 0, stream>>>(bits3, carryA, LA, sizesA, ncompA, out);
}

// Round 12
// 203.597 us; speedup vs baseline: 3.0514x; 3.0514x over previous
//
#include <hip/hip_runtime.h>
#include <stdint.h>

#define BATCH 16
#define H 512
#define W 512
#define HW (H * W)
#define NTOT (BATCH * HW)
#define NWORDS (NTOT / 64)      // 65536 packed words, 8 per row, 4096 per image

#define TPB 256
#define NBLKW ((NWORDS + TPB - 1) / TPB)

#define SROWS 16                // CCL strip = 16 rows
#define SWORDS 128              // words per CCL strip
#define SPIX 8192               // pixels per CCL strip
#define NSTRIPS (NWORDS / SWORDS)   // 512 strips (never straddle images)

// ---------------------------------------------------------------------------
// Union-find (global): atomicMin keeps parent <= child (monotone) -> acyclic;
// stale plain reads only cost retries. find_root_c path-compresses.
// ---------------------------------------------------------------------------
__device__ __forceinline__ int find_root_c(int* L, int x) {
    int r = x, p = L[r];
    while (p != r) { r = p; p = L[r]; }
    if (L[x] != r) atomicMin(&L[x], r);
    return r;
}

__device__ void merge_uf(int* L, int a, int b) {
    while (true) {
        a = find_root_c(L, a);
        b = find_root_c(L, b);
        if (a == b) return;
        int lo = a < b ? a : b;
        int hi = a < b ? b : a;
        int old = atomicMin(&L[hi], lo);
        if (old == hi) return;
        a = lo; b = old;
    }
}

__device__ __forceinline__ int find_root_lds(int* P, int x) {
    int r = x, p = P[r];
    while (p != r) { r = p; p = P[r]; }
    return r;
}

__device__ void merge_lds(int* P, int a, int b) {
    while (true) {
        a = find_root_lds(P, a);
        b = find_root_lds(P, b);
        if (a == b) return;
        int lo = a < b ? a : b;
        int hi = a < b ? b : a;
        int old = atomicMin(&P[hi], lo);
        if (old == hi) return;
        a = lo; b = old;
    }
}

// start index of the run containing bit i of word m (base = pixel idx of bit0)
__device__ __forceinline__ int start_of(uint64_t m, int i, int cv, int base) {
    uint64_t below = i ? ((~m) & ((1ull << i) - 1)) : 0ull;
    if (below == 0) return (cv >= 0) ? cv : base;
    int hz = 63 - __builtin_clzll(below);
    return base + hz + 1;
}

// remove-small transform of one word (fg comps; pure function of CCL data)
__device__ uint64_t keep_word(const uint64_t* __restrict__ bits,
                              const int* __restrict__ carry, const int* __restrict__ L,
                              const int* __restrict__ sizes, const int* __restrict__ ncomp,
                              int minsz, int gw) {
    uint64_t m = bits[gw];
    uint64_t res = m;
    if (m && ncomp[gw >> 12] > 1) {
        int cv = carry[gw];
        int base = gw << 6;
        while (m) {
            int s = __builtin_ctzll(m);
            uint64_t rest = m >> s;
            uint64_t nr = ~rest;
            int len = nr ? __builtin_ctzll(nr) : (64 - s);
            uint64_t piece = ((len >= 64) ? ~0ull : ((1ull << len) - 1)) << s;
            int start = (s == 0 && cv >= 0) ? cv : (base + s);
            if (sizes[L[start]] < minsz) res &= ~piece;
            m &= ~piece;
        }
    }
    return res;
}

// fill-holes transform of one word (bg comps; needs inv=1 CCL data)
__device__ uint64_t fill_word(const uint64_t* __restrict__ bits,
                              const int* __restrict__ carry, const int* __restrict__ L,
                              const int* __restrict__ sizes, int minsz, int gw) {
    uint64_t fg = bits[gw];
    uint64_t bg = ~fg;
    uint64_t res = fg;
    int cv = carry[gw];
    int base = gw << 6;
    while (bg) {
        int s = __builtin_ctzll(bg);
        uint64_t rest = bg >> s;
        uint64_t nr = ~rest;
        int len = nr ? __builtin_ctzll(nr) : (64 - s);
        uint64_t piece = ((len >= 64) ? ~0ull : ((1ull << len) - 1)) << s;
        int start = (s == 0 && cv >= 0) ? cv : (base + s);
        if (sizes[L[start]] < minsz) res |= piece;
        bg &= ~piece;
    }
    return res;
}

// one morph output word from an LDS window; gyTop = global row of local row 0
template <int R, bool ERODE>
__device__ uint64_t morph_word_lds(const uint64_t* buf, int lrow, int w, int gyTop) {
    const uint64_t BORDER = ERODE ? ~0ull : 0ull;
    uint64_t res = ERODE ? ~0ull : 0ull;
#pragma unroll
    for (int dy = -R; dy <= R; ++dy) {
        int lr = lrow + dy;
        int gy = gyTop + lr;
        if (gy < 0 || gy >= H) continue;       // image border rows = identity
        int v = R * R - dy * dy;
        int kx = 0;
        while ((kx + 1) * (kx + 1) <= v) ++kx;
        uint64_t cur = buf[lr * 8 + w];
        uint64_t prv = (w > 0) ? buf[lr * 8 + w - 1] : BORDER;
        uint64_t nxt = (w < 7) ? buf[lr * 8 + w + 1] : BORDER;
        uint64_t acc = cur;
#pragma unroll
        for (int dx = 1; dx <= kx; ++dx) {
            uint64_t right = (cur >> dx) | (nxt << (64 - dx));
            uint64_t left  = (cur << dx) | (prv >> (64 - dx));
            if (ERODE) acc &= right & left;
            else       acc |= right | left;
        }
        if (ERODE) res &= acc;
        else       res |= acc;
    }
    return res;
}

// ---------------------------------------------------------------------------
// Strip-local CCL body (128 threads, 16-row strip): all intra-strip unions in
// LDS, publish depth-1 trees. par's first write happens after the first
// internal __syncthreads, so it may alias LDS read before the call.
// ---------------------------------------------------------------------------
__device__ void strip_ccl_body(uint64_t m, uint64_t* sw, int* scarry, int* par,
                               int blk, int t,
                               int* __restrict__ carry, int* __restrict__ L,
                               int* __restrict__ sizes, int* __restrict__ ncomp) {
    sw[t] = m;
    __syncthreads();

    if (t < SROWS) {                    // per-row carries
        int cv = -1;
        for (int i = 0; i < 8; ++i) {
            int lw = t * 8 + i;
            scarry[lw] = cv;
            uint64_t w = sw[lw];
            if (w >> 63) {
                uint64_t z = ~w;
                if (z == 0) { if (cv < 0) cv = lw << 6; }
                else { int hz = 63 - __builtin_clzll(z); cv = (lw << 6) + hz + 1; }
            } else cv = -1;
        }
    }
    __syncthreads();

    int cv = scarry[t];
    carry[blk * SWORDS + t] = (cv >= 0) ? (blk * SPIX + cv) : -1;
    int lbase = t << 6;
    uint64_t starts = m & ~((m << 1) | ((cv >= 0) ? 1ull : 0ull));
    uint64_t ss = starts;
    while (ss) {
        int s = __builtin_ctzll(ss);
        par[lbase + s] = lbase + s;
        ss &= ss - 1;
    }
    __syncthreads();

    if (t >= 8 && m) {                  // intra-strip vertical unions
        uint64_t up = sw[t - 8];
        uint64_t cand = m & up;
        if (cand) {
            uint64_t curprev = (t & 7) ? sw[t - 1] : 0ull;
            uint64_t upprev  = (t & 7) ? sw[t - 9] : 0ull;
            uint64_t curl = (m << 1) | (curprev >> 63);
            uint64_t upl  = (up << 1) | (upprev >> 63);
            cand &= ~(curl & upl);
            int cvu = scarry[t - 8];
            while (cand) {
                int i = __builtin_ctzll(cand);
                int sP = start_of(m, i, cv, lbase);
                int sQ = start_of(up, i, cvu, lbase - 512);
                merge_lds(par, sP, sQ);
                cand &= cand - 1;
            }
        }
    }
    __syncthreads();

    int gpix = blk * SPIX;              // publish depth-1 trees
    ss = starts;
    while (ss) {
        int s = __builtin_ctzll(ss);
        int ls = lbase + s;
        int r = find_root_lds(par, ls);
        L[gpix + ls] = gpix + r;
        if (r == ls) sizes[gpix + ls] = 0;
        ss &= ss - 1;
    }
    if (t == 0 && (blk & 31) == 0) ncomp[blk >> 5] = 0;   // 32 strips per image
}

// ---------------------------------------------------------------------------
// Kernels — masks bit-packed: bit i of word w = pixel w*64+i.
// ---------------------------------------------------------------------------

// Vectorized threshold+pack: float4 per thread (16B/lane), nibble OR-tree via
// shfl_xor within 16-lane groups, one word store per 16 lanes.
__global__ void k_thresh_pack4(const float4* __restrict__ in4,
                               uint64_t* __restrict__ bits) {
    int q = blockIdx.x * blockDim.x + threadIdx.x;    // quad index (4 px)
    if (q >= NTOT / 4) return;
    float4 v = in4[q];
    uint32_t nib = (v.x > 0.0f ? 1u : 0u) | (v.y > 0.0f ? 2u : 0u) |
                   (v.z > 0.0f ? 4u : 0u) | (v.w > 0.0f ? 8u : 0u);
    uint64_t val = (uint64_t)nib << (4 * (threadIdx.x & 15));
    val |= __shfl_xor(val, 1);
    val |= __shfl_xor(val, 2);
    val |= __shfl_xor(val, 4);
    val |= __shfl_xor(val, 8);
    if ((threadIdx.x & 15) == 0) bits[q >> 4] = val;
}

// Strip CCL on an existing bitmap (inv selects fg/bg labeling).
__global__ void k_strip_ccl(const uint64_t* __restrict__ bits, int inv,
                            int* __restrict__ carry, int* __restrict__ L,
                            int* __restrict__ sizes, int* __restrict__ ncomp) {
    __shared__ uint64_t sw[SWORDS];
    __shared__ int scarry[SWORDS];
    __shared__ int par[SPIX];
    int blk = blockIdx.x;
    int t = threadIdx.x;
    uint64_t inv64 = inv ? ~0ull : 0ull;
    uint64_t m = bits[blk * SWORDS + t] ^ inv64;
    strip_ccl_body(m, sw, scarry, par, blk, t, carry, L, sizes, ncomp);
}

// FUSED: remove_small_objects transform (CCL-set IN) + bg strip-CCL (set OUT).
__global__ void k_keep_strip(const uint64_t* __restrict__ bits,
                             const int* __restrict__ carryIn, const int* __restrict__ Lin,
                             const int* __restrict__ sizesIn, const int* __restrict__ ncompIn,
                             uint64_t* __restrict__ outBits,
                             int* __restrict__ carryOut, int* __restrict__ Lout,
                             int* __restrict__ sizesOut, int* __restrict__ ncompOut) {
    __shared__ uint64_t sw[SWORDS];
    __shared__ int scarry[SWORDS];
    __shared__ int par[SPIX];
    int blk = blockIdx.x;
    int t = threadIdx.x;
    int gw = blk * SWORDS + t;
    uint64_t kw = keep_word(bits, carryIn, Lin, sizesIn, ncompIn, 2000, gw);
    outBits[gw] = kw;
    strip_ccl_body(~kw, sw, scarry, par, blk, t, carryOut, Lout, sizesOut, ncompOut);
}

// Cross-strip unions — compact grid: only boundary-row words (y%16==0, y!=0).
__global__ void k_merge_bound(const uint64_t* __restrict__ bits, int inv,
                              const int* __restrict__ carry, int* __restrict__ L) {
    int tid = threadIdx.x;
    if (tid >= 248) return;             // 31 boundary rows x 8 words
    int img = blockIdx.x;
    int y = ((tid >> 3) + 1) * SROWS;
    int w = tid & 7;
    int gw = img * 4096 + y * 8 + w;
    uint64_t inv64 = inv ? ~0ull : 0ull;
    uint64_t cur = bits[gw] ^ inv64;
    uint64_t up  = bits[gw - 8] ^ inv64;
    uint64_t cand = cur & up;
    if (!cand) return;
    uint64_t curprev = w ? (bits[gw - 1] ^ inv64) : 0ull;
    uint64_t upprev  = w ? (bits[gw - 9] ^ inv64) : 0ull;
    uint64_t curl = (cur << 1) | (curprev >> 63);
    uint64_t upl  = (up << 1)  | (upprev >> 63);
    cand &= ~(curl & upl);
    if (!cand) return;
    int cvc = carry[gw], cvu = carry[gw - 8];
    int base = gw << 6;
    while (cand) {
        int i = __builtin_ctzll(cand);
        int sP = start_of(cur, i, cvc, base);
        int sQ = start_of(up, i, cvu, base - W);
        merge_uf(L, sP, sQ);
        cand &= cand - 1;
    }
}

// Word-granular flatten + size accumulation with per-block LDS hash.
__global__ void k_flatten_count(const uint64_t* __restrict__ bits, int inv,
                                const int* __restrict__ carry, int* __restrict__ L,
                                int* __restrict__ sizes, int* __restrict__ ncomp) {
    __shared__ int hk[128];
    __shared__ int hv[128];
    for (int i = threadIdx.x; i < 128; i += TPB) { hk[i] = -1; hv[i] = 0; }
    __syncthreads();

    int gw = blockIdx.x * blockDim.x + threadIdx.x;
    if (gw < NWORDS) {
        uint64_t inv64 = inv ? ~0ull : 0ull;
        uint64_t m = bits[gw] ^ inv64;
        if (m) {
            int cv = carry[gw];
            int base = gw << 6;
            while (m) {
                int s = __builtin_ctzll(m);
                uint64_t rest = m >> s;
                uint64_t nr = ~rest;
                int len = nr ? __builtin_ctzll(nr) : (64 - s);
                uint64_t piece = ((len >= 64) ? ~0ull : ((1ull << len) - 1)) << s;
                bool initial = !(s == 0 && cv >= 0);
                int start = initial ? (base + s) : cv;
                int r = find_root_c(L, start);
                if (initial && r == start) atomicAdd(&ncomp[gw >> 12], 1);
                int cnt = __popcll(piece);
                uint32_t h = ((uint32_t)r * 2654435761u) >> 25;
                bool done = false;
                for (int tt = 0; tt < 16; ++tt) {
                    int slot = (h + tt) & 127;
                    int k = hk[slot];
                    if (k == -1) k = atomicCAS(&hk[slot], -1, r);
                    if (k == -1 || k == r) { atomicAdd(&hv[slot], cnt); done = true; break; }
                }
                if (!done) atomicAdd(&sizes[r], cnt);
                m &= ~piece;
            }
        }
    }
    __syncthreads();
    for (int i = threadIdx.x; i < 128; i += TPB)
        if (hk[i] != -1) atomicAdd(&sizes[hk[i]], hv[i]);
}

// FUSED: fill_holes + erode(d2) + erode(d5) + dilate(d5) + CCL3 strip phase.
// One block per 16-row output strip (128 threads); 12-row halo each side ->
// 40-row LDS window; morph chain in LDS; result feeds strip_ccl_body directly
// (intra-block handoff). Reads CCL set B, writes bits3 + CCL set A.
__global__ void k_fill_morph_ccl(const uint64_t* __restrict__ bits,
                                 const int* __restrict__ carryB, const int* __restrict__ LB,
                                 const int* __restrict__ sizesB,
                                 uint64_t* __restrict__ bits3,
                                 int* __restrict__ carryA, int* __restrict__ LA,
                                 int* __restrict__ sizesA, int* __restrict__ ncompA) {
    __shared__ uint64_t sw[SWORDS];
    __shared__ int scarry[SWORDS];
    __shared__ union {
        int par[SPIX];                                     // 32 KB (CCL)
        struct { uint64_t A[320]; uint64_t B[320]; } mo;   // 5 KB (morph)
    } U;
    int s = blockIdx.x;                 // strip id (32 per image)
    int t = threadIdx.x;
    int img = s >> 5, si = s & 31;
    int gyTop = si * 16 - 12;

    for (int lw = t; lw < 320; lw += SWORDS) {   // load + fill-holes
        int gy = gyTop + (lw >> 3);
        int w = lw & 7;
        uint64_t v = 0;
        if (gy >= 0 && gy < H)
            v = fill_word(bits, carryB, LB, sizesB, 301, img * 4096 + gy * 8 + w);
        U.mo.A[lw] = v;
    }
    __syncthreads();
    for (int lw = t; lw < 320; lw += SWORDS) {   // erode disk(2): rows 2..37
        int lr = lw >> 3;
        if (lr >= 2 && lr <= 37) U.mo.B[lw] = morph_word_lds<2, true>(U.mo.A, lr, lw & 7, gyTop);
    }
    __syncthreads();
    for (int lw = t; lw < 320; lw += SWORDS) {   // erode disk(5): rows 7..32
        int lr = lw >> 3;
        if (lr >= 7 && lr <= 32) U.mo.A[lw] = morph_word_lds<5, true>(U.mo.B, lr, lw & 7, gyTop);
    }
    __syncthreads();
    for (int lw = t; lw < 320; lw += SWORDS) {   // dilate disk(5): rows 12..27
        int lr = lw >> 3;
        if (lr >= 12 && lr <= 27) U.mo.B[lw] = morph_word_lds<5, false>(U.mo.A, lr, lw & 7, gyTop);
    }
    __syncthreads();
    uint64_t m3 = U.mo.B[t + 96];       // local rows 12..27 = this strip
    bits3[s * SWORDS + t] = m3;
    // CCL3 strip phase straight from registers (par aliases mo — safe: all
    // mo.B reads happen before strip_ccl_body's first par write, which is
    // behind two __syncthreads)
    strip_ccl_body(m3, sw, scarry, U.par, s, t, carryA, LA, sizesA, ncompA);
}

// FUSED: remove_small_objects transform + dilate(disk1) + float4 cast.
__global__ void k_keep_dilate_float(const uint64_t* __restrict__ bits,
                                    const int* __restrict__ carry, const int* __restrict__ L,
                                    const int* __restrict__ sizes, const int* __restrict__ ncomp,
                                    float* __restrict__ out) {
    __shared__ uint64_t kb[10 * 8];     // rows y0-1 .. y0+8
    __shared__ uint64_t db[8 * 8];      // dilated output rows
    int blk = blockIdx.x;
    int img = blk >> 6;                 // 64 blocks per image
    int s = blk & 63;
    int y0 = s * 8;
    int t = threadIdx.x;

    if (t < 80) {
        int lr = t >> 3;
        int w = t & 7;
        int gy = y0 - 1 + lr;
        uint64_t v = 0;
        if (gy >= 0 && gy < H)
            v = keep_word(bits, carry, L, sizes, ncomp, 2000, img * 4096 + gy * 8 + w);
        kb[t] = v;
    }
    __syncthreads();
    if (t < 64) {
        int r = t >> 3, w = t & 7;
        uint64_t cur = kb[(r + 1) * 8 + w];
        uint64_t up  = kb[r * 8 + w];
        uint64_t dn  = kb[(r + 2) * 8 + w];
        uint64_t prv = w ? kb[(r + 1) * 8 + w - 1] : 0ull;
        uint64_t nxt = (w < 7) ? kb[(r + 1) * 8 + w + 1] : 0ull;
        db[t] = cur | up | dn | (cur << 1) | (prv >> 63) | (cur >> 1) | (nxt << 63);
    }
    __syncthreads();

    int q0 = t * 16;                    // 16 consecutive pixels per thread
    uint64_t wd = db[q0 >> 6];
    int sh = q0 & 63;
    float4* o = (float4*)(out + (size_t)img * HW + (size_t)y0 * W + q0);
#pragma unroll
    for (int k = 0; k < 4; ++k) {
        uint32_t nib = (uint32_t)(wd >> (sh + k * 4)) & 0xFu;
        float4 f;
        f.x = (nib & 1u) ? 1.0f : 0.0f;
        f.y = (nib & 2u) ? 1.0f : 0.0f;
        f.z = (nib & 4u) ? 1.0f : 0.0f;
        f.w = (nib & 8u) ? 1.0f : 0.0f;
        o[k] = f;
    }
}

// ---------------------------------------------------------------------------
// Host side — 11 dispatches total
// ---------------------------------------------------------------------------
extern "C" void kernel_launch(void* const* d_in, const int* in_sizes, int n_in,
                              void* d_out, int out_size, void* d_ws, size_t ws_size,
                              hipStream_t stream) {
    const float* in = (const float*)d_in[0];
    float* out = (float*)d_out;

    uint8_t* ws = (uint8_t*)d_ws;
    int* LA      = (int*)ws;                                  // 16 MB
    int* sizesA  = (int*)(ws + (size_t)NTOT * 4);             // 16 MB
    int* LB      = (int*)(ws + (size_t)NTOT * 8);             // 16 MB
    int* sizesB  = (int*)(ws + (size_t)NTOT * 12);            // 16 MB
    uint64_t* bits1 = (uint64_t*)(ws + (size_t)NTOT * 16);    // 512 KB
    uint64_t* bits2 = bits1 + NWORDS;                         // 512 KB
    uint64_t* bits3 = bits2 + NWORDS;                         // 512 KB
    int* carryA = (int*)(bits3 + NWORDS);                     // 256 KB
    int* carryB = carryA + NWORDS;                            // 256 KB
    int* ncompA = carryB + NWORDS;                            // 64 B
    int* ncompB = ncompA + BATCH;                             // 64 B

    // fg = mask > 0, packed (vectorized full-occupancy BW pass)
    k_thresh_pack4<<<(NTOT / 4 + TPB - 1) / TPB, TPB, 0, stream>>>((const float4*)in, bits1);

    // CCL1 (fg of bits1) -> set A
    k_strip_ccl<<<NSTRIPS, SWORDS, 0, stream>>>(bits1, 0, carryA, LA, sizesA, ncompA);
    k_merge_bound<<<BATCH, 256, 0, stream>>>(bits1, 0, carryA, LA);
    k_flatten_count<<<NBLKW, TPB, 0, stream>>>(bits1, 0, carryA, LA, sizesA, ncompA);

    // remove_small_objects(2000,guard) [set A] fused with CCL2 strip (bg) -> set B
    k_keep_strip<<<NSTRIPS, SWORDS, 0, stream>>>(bits1, carryA, LA, sizesA, ncompA,
                                                 bits2, carryB, LB, sizesB, ncompB);
    k_merge_bound<<<BATCH, 256, 0, stream>>>(bits2, 1, carryB, LB);
    k_flatten_count<<<NBLKW, TPB, 0, stream>>>(bits2, 1, carryB, LB, sizesB, ncompB);

    // fill_holes(<301) + erode(d2) + opening(d5) + CCL3 strip: set B -> bits3, set A
    k_fill_morph_ccl<<<NSTRIPS, SWORDS, 0, stream>>>(bits2, carryB, LB, sizesB,
                                                     bits3, carryA, LA, sizesA, ncompA);
    k_merge_bound<<<BATCH, 256, 0, stream>>>(bits3, 0, carryA, LA);
    k_flatten_count<<<NBLKW, TPB, 0, stream>>>(bits3, 0, carryA, LA, sizesA, ncompA);

    // remove_small_objects(2000,guard) + dilate(d1) + float4 out
    k_keep_dilate_float<<<BATCH * 64, TPB, 0, stream>>>(bits3, carryA, LA, sizesA, ncompA, out);
}